// Round 2
// baseline (646.178 us; speedup 1.0000x reference)
//
#include <hip/hip_runtime.h>
#include <math.h>

typedef float f32x4 __attribute__((ext_vector_type(4)));

#define BN_EPS 1e-5f

// ---------------------------------------------------------------------------
// async global->LDS, 16B per lane. LDS dst must be wave-uniform base; HW adds
// lane*16. Global src is per-lane.
// ---------------------------------------------------------------------------
__device__ __forceinline__ void async_ld16(const float* g, float* l) {
  __builtin_amdgcn_global_load_lds(
      (const __attribute__((address_space(1))) void*)g,
      (__attribute__((address_space(3))) void*)l, 16, 0, 0);
}

// ---------------------------------------------------------------------------
// K1: fused MLP 3->64->128 (BN+ReLU each), writes h2 TRANSPOSED: h2T[b][c][n]
// grid 128 blocks x 256 thr; block = (b, 64-point chunk)
// ---------------------------------------------------------------------------
__global__ __launch_bounds__(256) void k1_mlp(
    const float* __restrict__ x,
    const float* __restrict__ w1, const float* __restrict__ g1,
    const float* __restrict__ b1, const float* __restrict__ m1,
    const float* __restrict__ v1,
    const float* __restrict__ w2, const float* __restrict__ g2,
    const float* __restrict__ b2, const float* __restrict__ m2,
    const float* __restrict__ v2,
    float* __restrict__ h2T)
{
  __shared__ float w1s[64 * 3];
  __shared__ float s1c[64], o1c[64];
  __shared__ float w2s[64 * 132];   // [o][j], padded stride 132
  __shared__ float s2c[128], o2c[128];
  __shared__ float h1s[64 * 64];    // [o][n]

  const int tid = threadIdx.x;
  const int b = blockIdx.x >> 5;
  const int n0 = (blockIdx.x & 31) << 6;

  if (tid < 64) {
    float s = g1[tid] / sqrtf(v1[tid] + BN_EPS);
    s1c[tid] = s;
    o1c[tid] = b1[tid] - m1[tid] * s;
    w1s[tid * 3 + 0] = w1[tid * 3 + 0];
    w1s[tid * 3 + 1] = w1[tid * 3 + 1];
    w1s[tid * 3 + 2] = w1[tid * 3 + 2];
  }
  if (tid < 128) {
    float s = g2[tid] / sqrtf(v2[tid] + BN_EPS);
    s2c[tid] = s;
    o2c[tid] = b2[tid] - m2[tid] * s;
  }
  for (int it = 0; it < 32; ++it) {
    int idx = tid + (it << 8);          // 8192
    int o = idx & 63, j = idx >> 6;
    w2s[o * 132 + j] = w2[j * 64 + o];  // transpose in LDS
  }
  __syncthreads();

  const int n = tid & 63, half = tid >> 6;

  // phase 1: h1 for o in [half*16, half*16+16)
  const float* xp = x + ((size_t)(b << 11) + n0 + n) * 3;
  float xv0 = xp[0], xv1 = xp[1], xv2 = xp[2];
  for (int oo = 0; oo < 16; ++oo) {
    int o = (half << 4) + oo;
    float d = xv0 * w1s[o * 3] + xv1 * w1s[o * 3 + 1] + xv2 * w1s[o * 3 + 2];
    d = d * s1c[o] + o1c[o];
    h1s[o * 64 + n] = fmaxf(d, 0.f);
  }
  __syncthreads();

  // phase 2: j in [half*32, half*32+32)
  float acc[32];
  #pragma unroll
  for (int jj = 0; jj < 32; ++jj) acc[jj] = 0.f;
  const int j0 = half << 5;
  for (int o = 0; o < 64; ++o) {
    float a = h1s[o * 64 + n];
    const f32x4* wrow = (const f32x4*)&w2s[o * 132 + j0];
    #pragma unroll
    for (int jg = 0; jg < 8; ++jg) {
      f32x4 wv = wrow[jg];
      acc[jg * 4 + 0] = fmaf(a, wv[0], acc[jg * 4 + 0]);
      acc[jg * 4 + 1] = fmaf(a, wv[1], acc[jg * 4 + 1]);
      acc[jg * 4 + 2] = fmaf(a, wv[2], acc[jg * 4 + 2]);
      acc[jg * 4 + 3] = fmaf(a, wv[3], acc[jg * 4 + 3]);
    }
  }
  #pragma unroll
  for (int jj = 0; jj < 32; ++jj) {
    int j = j0 + jj;
    float vl = acc[jj] * s2c[j] + o2c[j];
    h2T[((size_t)b * 128 + j) * 2048 + n0 + n] = fmaxf(vl, 0.f);
  }
}

// ---------------------------------------------------------------------------
// K2: the big one. feat[b][k][o] = max_n  h2[b,n,:] . wb[k,o,:]
// (BN applied later; positive scale => commutes with max)
// grid 512 blocks (= (b,k) pair * 8 o-tiles of 128), 256 thr, 4x8 micro-tile,
// Wt resident in LDS, A chunks (64 n) double-buffered via global_load_lds.
// ---------------------------------------------------------------------------
__global__ __launch_bounds__(256) void k2_branch_max(
    const float* __restrict__ h2T, const float* __restrict__ wb,
    float* __restrict__ feat)
{
  __shared__ float Wt[128 * 132];    // [c][o] padded
  __shared__ float As[2 * 128 * 64]; // [buf][c][n] linear (global_load_lds)
  __shared__ float redm[4 * 16 * 8];

  const int tid = threadIdx.x;
  const int ot = blockIdx.x & 7;
  const int p = blockIdx.x >> 3;
  const int k = p & 15, b = p >> 4;
  const int o0 = ot << 7;
  const int lane = tid & 63, w = tid >> 6;
  const int r = lane >> 4, cg = lane & 15;
  const int csub = (lane & 15) << 2;

  const float* gA = h2T + (size_t)b * (128 * 2048);

  // async stage chunk 0 into buf 0
  #pragma unroll
  for (int q = 0; q < 8; ++q) {
    int rowb = (q << 4) + (w << 2);
    async_ld16(gA + (size_t)(rowb + r) * 2048 + csub, &As[rowb << 6]);
  }
  // stage Wt[c][o] = wb[k][o0+ol][c]
  {
    const float* wbk = wb + ((size_t)(k << 10) + o0) * 128;
    for (int it = 0; it < 16; ++it) {
      int idx = tid + (it << 8);        // 4096 float4s
      int ol = idx >> 5, cc = (idx & 31) << 2;
      f32x4 v = *(const f32x4*)(wbk + (size_t)ol * 128 + cc);
      Wt[(cc + 0) * 132 + ol] = v[0];
      Wt[(cc + 1) * 132 + ol] = v[1];
      Wt[(cc + 2) * 132 + ol] = v[2];
      Wt[(cc + 3) * 132 + ol] = v[3];
    }
  }
  __syncthreads();

  const int aoff = (w << 4) + (r << 2);
  const int woa = cg << 2;
  const int wob = 64 + (cg << 2);

  float mx[8];
  #pragma unroll
  for (int j = 0; j < 8; ++j) mx[j] = -3.4e38f;

  for (int nc = 0; nc < 32; ++nc) {
    const int buf = nc & 1;
    if (nc + 1 < 32) {  // prefetch next chunk into other buffer
      const float* gn = gA + ((nc + 1) << 6);
      float* dst = &As[(buf ^ 1) << 13];
      #pragma unroll
      for (int q = 0; q < 8; ++q) {
        int rowb = (q << 4) + (w << 2);
        async_ld16(gn + (size_t)(rowb + r) * 2048 + csub, dst + (rowb << 6));
      }
    }
    float acc[4][8];
    #pragma unroll
    for (int i = 0; i < 4; ++i) {
      #pragma unroll
      for (int j = 0; j < 8; ++j) acc[i][j] = 0.f;
    }
    const float* Ab = &As[buf << 13];
    #pragma unroll 8
    for (int kk = 0; kk < 128; ++kk) {
      f32x4 a4 = *(const f32x4*)(Ab + (kk << 6) + aoff);
      f32x4 wa = *(const f32x4*)(&Wt[kk * 132 + woa]);
      f32x4 wc = *(const f32x4*)(&Wt[kk * 132 + wob]);
      #pragma unroll
      for (int i = 0; i < 4; ++i) {
        #pragma unroll
        for (int j = 0; j < 4; ++j) {
          acc[i][j]     = fmaf(a4[i], wa[j], acc[i][j]);
          acc[i][j + 4] = fmaf(a4[i], wc[j], acc[i][j + 4]);
        }
      }
    }
    #pragma unroll
    for (int j = 0; j < 8; ++j) {
      float m = fmaxf(fmaxf(acc[0][j], acc[1][j]), fmaxf(acc[2][j], acc[3][j]));
      mx[j] = fmaxf(mx[j], m);
    }
    __syncthreads();  // drains vmcnt -> prefetched buffer ready; frees cur buf
  }

  // reduce max across r-groups (xor16) and waves pairs in-wave (xor32)
  #pragma unroll
  for (int j = 0; j < 8; ++j) {
    float m = mx[j];
    m = fmaxf(m, __shfl_xor(m, 16));
    m = fmaxf(m, __shfl_xor(m, 32));
    mx[j] = m;
  }
  if (lane < 16) {
    #pragma unroll
    for (int j = 0; j < 8; ++j) redm[((w << 4) + lane) * 8 + j] = mx[j];
  }
  __syncthreads();
  if (tid < 128) {
    int cgf = tid >> 3, j = tid & 7;
    float m = fmaxf(fmaxf(redm[cgf * 8 + j], redm[(16 + cgf) * 8 + j]),
                    fmaxf(redm[(32 + cgf) * 8 + j], redm[(48 + cgf) * 8 + j]));
    int o = (cgf << 2) + (j & 3) + ((j >> 2) << 6);
    feat[((size_t)(b * 16 + k) << 10) + o0 + o] = m;
  }
}

// ---------------------------------------------------------------------------
// K3a: caps[b][i][e] = squash_e( BN(feat[b][e][i]) ),  e=16
// grid 16 x 256
// ---------------------------------------------------------------------------
__global__ __launch_bounds__(256) void k3a_caps(
    const float* __restrict__ feat,
    const float* __restrict__ gb, const float* __restrict__ bb,
    const float* __restrict__ mb, const float* __restrict__ vb,
    float* __restrict__ caps)
{
  int g = blockIdx.x * 256 + threadIdx.x;  // 4096
  int b = g >> 10, i = g & 1023;
  float val[16];
  float ss = 0.f;
  #pragma unroll
  for (int e = 0; e < 16; ++e) {
    int ei = (e << 10) + i;
    float f = feat[((size_t)(b << 4) << 10) + ei];
    float sc = gb[ei] / sqrtf(vb[ei] + BN_EPS);
    float vv = (f - mb[ei]) * sc + bb[ei];
    val[e] = vv;
    ss += vv * vv;
  }
  float nrm = sqrtf(ss);
  float scl = nrm / (1.f + nrm * nrm);
  f32x4* cp = (f32x4*)&caps[(size_t)((b << 10) + i) << 4];
  #pragma unroll
  for (int q = 0; q < 4; ++q) {
    f32x4 v;
    v[0] = val[q * 4 + 0] * scl; v[1] = val[q * 4 + 1] * scl;
    v[2] = val[q * 4 + 2] * scl; v[3] = val[q * 4 + 3] * scl;
    cp[q] = v;
  }
}

// ---------------------------------------------------------------------------
// K3b: u[b][o][i][v] = sum_e caps[b][i][e] * Wc[o][i][e][v]
//      + partial s0 (= sum_i u) per (o, i-tile)
// grid 1024 blocks (o=32 x itile=32), 256 thr
// ---------------------------------------------------------------------------
__global__ __launch_bounds__(256) void k3b_u(
    const float* __restrict__ caps, const float* __restrict__ Wc,
    float* __restrict__ u, float* __restrict__ s0p)
{
  __shared__ float caps_l[4 * 32 * 16];  // [b][il][e]
  __shared__ float s_red[16 * 32];       // [w*4+b][v]

  const int tid = threadIdx.x;
  const int o = blockIdx.x & 31, it = blockIdx.x >> 5;
  const int i0 = it << 5;

  for (int ld = 0; ld < 8; ++ld) {
    int idx = tid + (ld << 8);  // 2048 = b*512 + il*16 + e
    int bq = idx >> 9, il = (idx >> 4) & 31, e = idx & 15;
    caps_l[idx] = caps[(size_t)(((bq << 10) + i0 + il) << 4) + e];
  }
  __syncthreads();

  const int w = tid >> 6, lane = tid & 63;
  const int eh = lane >> 5, v = lane & 31;
  float s0acc[4] = {0.f, 0.f, 0.f, 0.f};

  for (int ii = 0; ii < 8; ++ii) {
    int il = (w << 3) + ii;
    int i = i0 + il;
    const float* wc = Wc + ((size_t)(o << 10) + i) * 512 + (eh << 8) + v;
    float acc[4] = {0.f, 0.f, 0.f, 0.f};
    #pragma unroll
    for (int ee = 0; ee < 8; ++ee) {
      float wv = wc[ee * 32];
      int e = (eh << 3) + ee;
      #pragma unroll
      for (int bq = 0; bq < 4; ++bq)
        acc[bq] = fmaf(caps_l[bq * 512 + il * 16 + e], wv, acc[bq]);
    }
    #pragma unroll
    for (int bq = 0; bq < 4; ++bq) {
      acc[bq] += __shfl_xor(acc[bq], 32);
      if (eh == 0) {
        u[(size_t)((((bq << 5) + o) << 10) + i) * 32 + v] = acc[bq];
        s0acc[bq] += acc[bq];
      }
    }
  }
  if (eh == 0) {
    #pragma unroll
    for (int bq = 0; bq < 4; ++bq) s_red[((w << 2) + bq) * 32 + v] = s0acc[bq];
  }
  __syncthreads();
  if (tid < 128) {
    int bq = tid >> 5, vv = tid & 31;
    float s = s_red[bq * 32 + vv] + s_red[(4 + bq) * 32 + vv] +
              s_red[(8 + bq) * 32 + vv] + s_red[(12 + bq) * 32 + vv];
    s0p[(size_t)(((bq << 5) + it) << 5 | o) * 32 + vv] = s;
  }
}

// ---------------------------------------------------------------------------
// K4: out = squash_v( prescale * sum_it spart[b][it][o][v] )
// grid 4 (b) x 256
// ---------------------------------------------------------------------------
__global__ __launch_bounds__(256) void k4_squash(
    const float* __restrict__ sp, float* __restrict__ out, float prescale)
{
  const int tid = threadIdx.x;
  const int b = blockIdx.x;
  const int o = tid >> 3, vq = (tid & 7) << 2;
  f32x4 acc = {0.f, 0.f, 0.f, 0.f};
  for (int it = 0; it < 32; ++it) {
    f32x4 p = *(const f32x4*)(sp + (size_t)(((b << 5) + it) << 5 | o) * 32 + vq);
    acc += p;
  }
  acc *= prescale;
  float ss = acc[0] * acc[0] + acc[1] * acc[1] + acc[2] * acc[2] + acc[3] * acc[3];
  ss += __shfl_xor(ss, 1);
  ss += __shfl_xor(ss, 2);
  ss += __shfl_xor(ss, 4);
  float nrm = sqrtf(ss);
  float scl = nrm / (1.f + nrm * nrm);
  f32x4 r = acc * scl;
  *(f32x4*)(out + (size_t)((b << 5) + o) * 32 + vq) = r;
}

// ---------------------------------------------------------------------------
// K5: one routing pass over u.
// pass 0: bl = agree(a0,u);          store bl -> bout; c=softmax_o(bl); s1 += c*u
// pass 1: bl = bprev + agree(a1,u);                    c=softmax_o(bl); s2 += c*u
// grid 128 blocks (b=4 x itile=32), 256 thr; wave handles 8 i's.
// ---------------------------------------------------------------------------
__global__ __launch_bounds__(256) void k5_route(
    const float* __restrict__ u, const float* __restrict__ aprev,
    const float* __restrict__ bprev, float* __restrict__ bout,
    float* __restrict__ spart, int pass)
{
  __shared__ float a_l[32 * 33];
  __shared__ float u_l[4 * 32 * 33];
  __shared__ float s_red[4 * 32 * 33];

  const int tid = threadIdx.x;
  const int b = blockIdx.x >> 5, it = blockIdx.x & 31;
  const int i0 = it << 5;

  for (int ld = 0; ld < 4; ++ld) {
    int idx = tid + (ld << 8);  // 1024
    int o = idx >> 5, v = idx & 31;
    a_l[o * 33 + v] = aprev[((b << 5) + o) * 32 + v];
  }
  __syncthreads();

  const int w = tid >> 6, lane = tid & 63;
  const int ln5 = lane & 31, hb = lane >> 5;
  float* uw = &u_l[w * 1056];

  float sacc[16];
  #pragma unroll
  for (int q = 0; q < 16; ++q) sacc[q] = 0.f;

  for (int ii = 0; ii < 8; ++ii) {
    int i = i0 + (w << 3) + ii;
    // stage u block [32 o][32 v] (wave-local; compiler inserts lgkm waits)
    #pragma unroll
    for (int rr = 0; rr < 16; ++rr) {
      int o = (rr << 1) + hb;
      uw[o * 33 + ln5] = u[(size_t)((((b << 5) + o) << 10) + i) * 32 + ln5];
    }
    // agree[o]: lane (ln5=o, hb=v-half)
    float ag = 0.f;
    #pragma unroll
    for (int q = 0; q < 16; ++q) {
      int vv = (hb << 4) + q;
      ag = fmaf(a_l[ln5 * 33 + vv], uw[ln5 * 33 + vv], ag);
    }
    ag += __shfl_xor(ag, 32);
    float bl = ag;
    if (pass == 1) bl += bprev[(((b << 5) + ln5) << 10) + i];
    if (pass == 0 && hb == 0) bout[(((b << 5) + ln5) << 10) + i] = bl;
    // softmax over o (32 values, one per lane within each half)
    float m = bl;
    m = fmaxf(m, __shfl_xor(m, 1));
    m = fmaxf(m, __shfl_xor(m, 2));
    m = fmaxf(m, __shfl_xor(m, 4));
    m = fmaxf(m, __shfl_xor(m, 8));
    m = fmaxf(m, __shfl_xor(m, 16));
    float e = expf(bl - m);
    float sm = e;
    sm += __shfl_xor(sm, 1);
    sm += __shfl_xor(sm, 2);
    sm += __shfl_xor(sm, 4);
    sm += __shfl_xor(sm, 8);
    sm += __shfl_xor(sm, 16);
    float c = e / sm;
    #pragma unroll
    for (int q = 0; q < 16; ++q) {
      int vv = (hb << 4) + q;
      sacc[q] = fmaf(c, uw[ln5 * 33 + vv], sacc[q]);
    }
  }
  #pragma unroll
  for (int q = 0; q < 16; ++q)
    s_red[w * 1056 + ln5 * 33 + (hb << 4) + q] = sacc[q];
  __syncthreads();
  for (int ld = 0; ld < 4; ++ld) {
    int idx = tid + (ld << 8);
    int o = idx >> 5, vv = idx & 31;
    float s = s_red[o * 33 + vv] + s_red[1056 + o * 33 + vv] +
              s_red[2112 + o * 33 + vv] + s_red[3168 + o * 33 + vv];
    spart[(size_t)(((b << 5) + it) << 5 | o) * 32 + vv] = s;
  }
}

// ---------------------------------------------------------------------------
extern "C" void kernel_launch(void* const* d_in, const int* in_sizes, int n_in,
                              void* d_out, int out_size, void* d_ws, size_t ws_size,
                              hipStream_t stream) {
  const float* x  = (const float*)d_in[0];
  const float* w1 = (const float*)d_in[1];
  const float* g1 = (const float*)d_in[2];
  const float* b1 = (const float*)d_in[3];
  const float* m1 = (const float*)d_in[4];
  const float* v1 = (const float*)d_in[5];
  const float* w2 = (const float*)d_in[6];
  const float* g2 = (const float*)d_in[7];
  const float* b2 = (const float*)d_in[8];
  const float* m2 = (const float*)d_in[9];
  const float* v2 = (const float*)d_in[10];
  const float* wb = (const float*)d_in[11];
  const float* gb = (const float*)d_in[12];
  const float* bb = (const float*)d_in[13];
  const float* mb = (const float*)d_in[14];
  const float* vb = (const float*)d_in[15];
  const float* Wc = (const float*)d_in[16];
  float* out = (float*)d_out;
  float* ws = (float*)d_ws;

  // workspace layout (floats); everything is fully written before read,
  // so no zero-init needed despite 0xAA poisoning.
  float* h2T  = ws + 0;         // 4*128*2048      = 1048576
  float* feat = ws + 1048576;   // 4*16*1024       = 65536
  float* caps = ws + 1114112;   // 4*1024*16       = 65536
  float* u    = ws + 1179648;   // 4*32*1024*32    = 4194304
  float* s0p  = ws + 5373952;   // 4*32*32*32      = 131072
  float* s1p  = ws + 5505024;   // 131072
  float* s2p  = ws + 5636096;   // 131072
  float* a0   = ws + 5767168;   // 4096
  float* a1   = ws + 5771264;   // 4096
  float* b1l  = ws + 5775360;   // 4*32*1024       = 131072
  // total 5906432 floats = 23.6 MB

  k1_mlp<<<128, 256, 0, stream>>>(x, w1, g1, b1, m1, v1,
                                  w2, g2, b2, m2, v2, h2T);
  k2_branch_max<<<512, 256, 0, stream>>>(h2T, wb, feat);
  k3a_caps<<<16, 256, 0, stream>>>(feat, gb, bb, mb, vb, caps);
  k3b_u<<<1024, 256, 0, stream>>>(caps, Wc, u, s0p);
  k4_squash<<<4, 256, 0, stream>>>(s0p, a0, 1.f / 32.f);
  k5_route<<<128, 256, 0, stream>>>(u, a0, b1l, b1l, s1p, 0);
  k4_squash<<<4, 256, 0, stream>>>(s1p, a1, 1.f);
  k5_route<<<128, 256, 0, stream>>>(u, a1, b1l, b1l, s2p, 1);
  k4_squash<<<4, 256, 0, stream>>>(s2p, out, 1.f);
}